// Round 17
// baseline (2919.135 us; speedup 1.0000x reference)
//
#include <hip/hip_runtime.h>
#include <cstdint>
#include <cstddef>

#define BATCH  128
#define SEQT   512
#define EMB_D  300
#define VOCABN 5000
#define KP0    320
#define NU0    256
#define NU1    512
#define NU2    256
#define NDENSE 64
#define RING   16
#define LIM    8192

typedef unsigned short ushortT;
typedef __attribute__((ext_vector_type(8))) short bf16x8;
typedef __attribute__((ext_vector_type(8))) unsigned short u16x8;
typedef __attribute__((ext_vector_type(4))) unsigned short u16x4;
typedef __attribute__((ext_vector_type(4))) unsigned u32x4;
typedef __attribute__((ext_vector_type(4))) float f32x4;

#define AGT __HIP_MEMORY_SCOPE_AGENT

static __device__ __forceinline__ unsigned short f2bf(float x) {
    union { float f; unsigned u; } v; v.f = x;
    const unsigned r = v.u + 0x7FFFu + ((v.u >> 16) & 1u);
    return (unsigned short)(r >> 16);
}
static __device__ __forceinline__ float bf2f(unsigned short b) {
    union { unsigned u; float f; } v; v.u = ((unsigned)b) << 16;
    return v.f;
}
static __device__ __forceinline__ float sigmoidf_(float x) {
    return 1.f / (1.f + __expf(-x));
}
static __device__ __forceinline__ unsigned ald(const unsigned* p) {
    return __hip_atomic_load((unsigned*)p, __ATOMIC_RELAXED, AGT);
}
static __device__ __forceinline__ void ast(unsigned* p, unsigned v) {
    __hip_atomic_store(p, v, __ATOMIC_RELAXED, AGT);
}
// coherent wide VMEM (device-scope, no L2 flush)
static __device__ __forceinline__ void ld4u(u32x4* d, const void* p) {
    asm volatile("global_load_dwordx4 %0, %1, off sc0 sc1"
                 : "=&v"(*d) : "v"(p) : "memory");
}
static __device__ __forceinline__ void st4c(void* p, unsigned v) {
    asm volatile("global_store_dword %0, %1, off sc0 sc1"
                 :: "v"(p), "v"(v) : "memory");
}
static __device__ __forceinline__ void wait0() {
    asm volatile("s_waitcnt vmcnt(0)" ::: "memory");
    __builtin_amdgcn_sched_barrier(0);
}

// ---------------------------------------------------------------------------
// One-time converts
// ---------------------------------------------------------------------------
__global__ __launch_bounds__(256) void convert_WT(
    const float* __restrict__ W, ushortT* __restrict__ WbfT,
    int K, int NG, int KP, int total)
{
    for (int idx = blockIdx.x * 256 + threadIdx.x; idx < total; idx += gridDim.x * 256) {
        const int m = idx / KP, k = idx - m * KP;
        WbfT[idx] = (k < K) ? f2bf(W[(size_t)k * NG + m]) : (ushortT)0;
    }
}
__global__ __launch_bounds__(256) void convert_emb(
    const float* __restrict__ emb, ushortT* __restrict__ embbf)
{
    const int total = VOCABN * KP0;
    for (int idx = blockIdx.x * 256 + threadIdx.x; idx < total; idx += gridDim.x * 256) {
        const int v = idx / KP0, k = idx - v * KP0;
        embbf[idx] = (k < EMB_D) ? f2bf(emb[(size_t)v * EMB_D + k]) : (ushortT)0;
    }
}

// ---------------------------------------------------------------------------
// Precompute ALL of xg0 (untagged bf16): xg0[t][g][1024][16].
// ---------------------------------------------------------------------------
__global__ __launch_bounds__(256) void gemm_xg0(
    const ushortT* __restrict__ embbf,
    const int*   __restrict__ tokens,
    const ushortT* __restrict__ W0T,     // [1024][KP0]
    const float* __restrict__ bias,
    ushortT* __restrict__ xg0)
{
    __shared__ ushortT Wl[128][32];
    __shared__ ushortT Xl[128][32];
    __shared__ int tokL[128];

    const int tid = threadIdx.x;
    const int t   = blockIdx.x;
    const int m0  = blockIdx.y * 128;
    const int wv  = tid >> 6;
    const int lane = tid & 63;
    const int lo  = lane & 15;
    const int hi  = lane >> 4;

    if (tid < 128) tokL[tid] = tokens[tid * SEQT + t];
    __syncthreads();

    f32x4 acc[2][8];
    #pragma unroll
    for (int s = 0; s < 2; ++s)
        #pragma unroll
        for (int n = 0; n < 8; ++n)
            acc[s][n] = f32x4{0.f, 0.f, 0.f, 0.f};

    for (int k0 = 0; k0 < KP0; k0 += 32) {
        #pragma unroll
        for (int it = 0; it < 2; ++it) {
            const int idx = tid + it * 256;
            const int row = idx >> 2, gq = idx & 3;
            const int gs  = gq ^ ((row >> 1) & 3);
            *(u16x8*)&Wl[row][gs * 8] =
                *(const u16x8*)(W0T + (size_t)(m0 + row) * KP0 + k0 + gq * 8);
            *(u16x8*)&Xl[row][gs * 8] =
                *(const u16x8*)(embbf + (size_t)tokL[row] * KP0 + k0 + gq * 8);
        }
        __syncthreads();

        bf16x8 xfr[8];
        #pragma unroll
        for (int n = 0; n < 8; ++n) {
            const int row = n * 16 + lo;
            xfr[n] = *(const bf16x8*)&Xl[row][(hi ^ ((row >> 1) & 3)) * 8];
        }
        #pragma unroll
        for (int s = 0; s < 2; ++s) {
            const int row = wv * 32 + s * 16 + lo;
            const bf16x8 a = *(const bf16x8*)&Wl[row][(hi ^ ((row >> 1) & 3)) * 8];
            #pragma unroll
            for (int n = 0; n < 8; ++n)
                acc[s][n] = __builtin_amdgcn_mfma_f32_16x16x32_bf16(a, xfr[n], acc[s][n], 0, 0, 0);
        }
        __syncthreads();
    }

    #pragma unroll
    for (int s = 0; s < 2; ++s)
        #pragma unroll
        for (int j = 0; j < 4; ++j) {
            const int m = m0 + wv * 32 + s * 16 + hi * 4 + j;
            const float bi = bias[m];
            #pragma unroll
            for (int n = 0; n < 8; ++n)
                xg0[(((size_t)t * 8 + n) * 1024 + m) * 16 + lo] = f2bf(acc[s][n][j] + bi);
        }
}

// ---------------------------------------------------------------------------
// Recurrence role with TAGGED-DATA sync. h ring: [RING][128][U] u32, each
// word = (tag<<16)|bf16, tag = producing step + 1. Consumer retry-loads its
// share until all tags current — no flags, no drains on the critical path.
// One barrier/step; LDS h-stage parity double-buffered. Progress flags
// published every 8 steps only for ring-overwrite guards.
// ---------------------------------------------------------------------------
template<int U_, bool XTAG, int MARG>
__device__ void rec_role(
    int rid,
    const float* __restrict__ Umat,
    const void* __restrict__ xgsrc, int xmask,   // tagged u32 or plain bf16
    unsigned* __restrict__ hring,                // [RING][128][U_] u32
    unsigned* Fguard, int nGd,
    unsigned* Fpub,
    char* smem)
{
    constexpr int NGu = 4 * U_;
    constexpr int KT  = U_ / 32;
    constexpr int GR  = U_ / 8;      // 8-elem granules per row
    constexpr int TPT = U_ / 16;     // tagged words per thread (h stage)
    constexpr int NV  = TPT / 4;     // dwordx4 loads per thread
    constexpr int NGR = TPT / 8;     // granules per thread

    ushortT* hstage = (ushortT*)smem;            // [2][16][U_] bf16

    const int tid = threadIdx.x, w = tid >> 6, lane = tid & 63;
    const int lo = lane & 15, hi = lane >> 4;
    const int grp = rid & 7, wgj = rid >> 3;
    const int b0 = grp * 16, J = wgj * 64;
    const int jcol = J + w * 16 + lo;
    const int srow = tid >> 4;                   // stage row 0..15
    const int scol = (tid & 15) * TPT;           // stage col base
    const size_t S = (size_t)128 * U_;

    // persistent B-fragments (all 4 gates for this thread's column)
    bf16x8 bfr[4][KT];
    #pragma unroll
    for (int g = 0; g < 4; ++g)
        #pragma unroll
        for (int kt = 0; kt < KT; ++kt) {
            const float* up = Umat + (size_t)(kt * 32 + hi * 8) * NGu + g * U_ + jcol;
            bf16x8 v;
            #pragma unroll
            for (int i = 0; i < 8; ++i) v[i] = (short)f2bf(up[(size_t)i * NGu]);
            bfr[g][kt] = v;
        }

    float creg[4] = {0.f, 0.f, 0.f, 0.f};

    for (int t = 0; t < SEQT; ++t) {
        // ---- ring-overwrite guard (every 8 steps, wave0, off critical path) ----
        if (nGd && (t & 7) == 0 && w == 0) {
            int gd = 0; bool ok;
            do {
                bool pr = true;
                for (int i = lane; i < nGd; i += 64)
                    pr = pr && ((int)ald(&Fguard[i * 16]) >= t - MARG);
                ok = __all(pr);
                if (!ok) __builtin_amdgcn_s_sleep(8);
            } while (!ok && ++gd < LIM);
        }

        // ---- issue xg + h loads together ----
        u32x4 xw[4];
        float xg[4][4];
        if (XTAG) {
            const unsigned* xb = (const unsigned*)xgsrc
                + ((size_t)(t & xmask) * 8 + grp) * NGu * 16;
            #pragma unroll
            for (int g = 0; g < 4; ++g)
                ld4u(&xw[g], xb + ((size_t)g * U_ + jcol) * 16 + hi * 4);
        } else {
            const ushortT* xb = (const ushortT*)xgsrc
                + ((size_t)(t & xmask) * 8 + grp) * NGu * 16;
            #pragma unroll
            for (int g = 0; g < 4; ++g) {
                const u16x4 v = *(const u16x4*)(xb + ((size_t)g * U_ + jcol) * 16 + hi * 4);
                #pragma unroll
                for (int e = 0; e < 4; ++e) xg[g][e] = bf2f(v[e]);
            }
        }
        u32x4 hv[NV];
        const unsigned* hp = nullptr;
        if (t > 0) {
            hp = hring + (size_t)((t - 1) & (RING - 1)) * S + (size_t)(b0 + srow) * U_ + scol;
            #pragma unroll
            for (int q = 0; q < NV; ++q) ld4u(&hv[q], hp + q * 4);
        }
        wait0();

        // ---- validate h tags (retry), extract to LDS ----
        if (t > 0) {
            const unsigned exp = (unsigned)t;
            int gd = 0;
            for (;;) {
                bool ok = true;
                #pragma unroll
                for (int q = 0; q < NV; ++q)
                    #pragma unroll
                    for (int e = 0; e < 4; ++e)
                        ok = ok && ((hv[q][e] >> 16) == exp);
                if (ok || ++gd >= LIM) break;
                __builtin_amdgcn_s_sleep(1);
                #pragma unroll
                for (int q = 0; q < NV; ++q) ld4u(&hv[q], hp + q * 4);
                wait0();
            }
            ushortT* hb = hstage + (size_t)(t & 1) * 16 * U_;
            #pragma unroll
            for (int gr = 0; gr < NGR; ++gr) {
                u16x8 v;
                #pragma unroll
                for (int e = 0; e < 4; ++e) v[e]     = (ushortT)hv[gr * 2][e];
                #pragma unroll
                for (int e = 0; e < 4; ++e) v[4 + e] = (ushortT)hv[gr * 2 + 1][e];
                const int gi = scol / 8 + gr;
                *(u16x8*)&hb[(srow * GR + (gi ^ (srow & 7))) * 8] = v;
            }
        }
        // ---- validate xg tags (retry, rarely needed: workers run ahead) ----
        if (XTAG) {
            const unsigned* xb = (const unsigned*)xgsrc
                + ((size_t)(t & xmask) * 8 + grp) * NGu * 16;
            const unsigned exp = (unsigned)(t + 1);
            int gd = 0;
            for (;;) {
                bool ok = true;
                #pragma unroll
                for (int g = 0; g < 4; ++g)
                    #pragma unroll
                    for (int e = 0; e < 4; ++e)
                        ok = ok && ((xw[g][e] >> 16) == exp);
                if (ok || ++gd >= LIM) break;
                __builtin_amdgcn_s_sleep(1);
                #pragma unroll
                for (int g = 0; g < 4; ++g)
                    ld4u(&xw[g], xb + ((size_t)g * U_ + jcol) * 16 + hi * 4);
                wait0();
            }
            #pragma unroll
            for (int g = 0; g < 4; ++g)
                #pragma unroll
                for (int e = 0; e < 4; ++e)
                    xg[g][e] = bf2f((ushortT)xw[g][e]);
        }
        __syncthreads();   // ONLY barrier: hstage[par] ready

        // ---- 4 gate MFMA chains ----
        f32x4 acc[4];
        #pragma unroll
        for (int g = 0; g < 4; ++g) acc[g] = f32x4{0.f, 0.f, 0.f, 0.f};
        if (t > 0) {
            const ushortT* hb = hstage + (size_t)(t & 1) * 16 * U_;
            #pragma unroll
            for (int kt = 0; kt < KT; ++kt) {
                const int gs = (kt * 4 + hi) ^ (lo & 7);
                const bf16x8 a = *(const bf16x8*)&hb[(lo * GR + gs) * 8];
                #pragma unroll
                for (int g = 0; g < 4; ++g)
                    acc[g] = __builtin_amdgcn_mfma_f32_16x16x32_bf16(a, bfr[g][kt], acc[g], 0, 0, 0);
            }
        }

        // ---- gates; update c; store tagged h (fire-and-forget) ----
        unsigned* hw = hring + (size_t)(t & (RING - 1)) * S;
        const unsigned tg = ((unsigned)(t + 1)) << 16;
        #pragma unroll
        for (int r = 0; r < 4; ++r) {
            const float i_ = sigmoidf_(acc[0][r] + xg[0][r]);
            const float f_ = sigmoidf_(acc[1][r] + xg[1][r]);
            const float cc = fmaxf(acc[2][r] + xg[2][r], 0.f);
            const float o_ = sigmoidf_(acc[3][r] + xg[3][r]);
            creg[r] = f_ * creg[r] + i_ * cc;
            const float hn = o_ * fmaxf(creg[r], 0.f);
            st4c(&hw[(size_t)(b0 + hi * 4 + r) * U_ + jcol], tg | (unsigned)f2bf(hn));
        }
        // progress flag for ring guards (every 8 steps; read-completion claim)
        if (Fpub && (t & 7) == 7 && tid == 0)
            ast(Fpub, (unsigned)(t + 1));
    }
}

// ---------------------------------------------------------------------------
// GEMM worker with tagged h consumption: per k-chunk retry-load tagged h,
// extract to LDS, MFMA; tagged xg stores; progress flag every iteration.
// ---------------------------------------------------------------------------
template<int MC, int NG, int KP, int P>
__device__ void worker_role(
    int mtile, int phase,
    const ushortT* __restrict__ WT,      // [NG][KP] bf16
    const float* __restrict__ bias,
    const unsigned* __restrict__ hring,  // [RING][128][KP] u32 tagged
    unsigned* __restrict__ xgring,       // [RING][8][NG][16] u32 tagged
    unsigned* Fguard, int nGd,
    unsigned* Fpub,
    char* smem)
{
    constexpr int GRW = KP / 8;
    constexpr int NC  = KP / 32;
    constexpr int WR  = MC / 4;
    constexpr int MT  = WR / 16;
    ushortT* Wl = (ushortT*)smem;                           // [MC][KP] swizzled
    ushortT* Xl = (ushortT*)(smem + (size_t)MC * KP * 2);   // [128][32]

    const int tid = threadIdx.x, w = tid >> 6, lane = tid & 63;
    const int lo = lane & 15, hi = lane >> 4;
    const int m0 = mtile * MC;
    const int crow = tid >> 1;
    const int ccol = (tid & 1) * 16;
    const int cg0  = ccol / 8;

    for (int i = tid; i < MC * GRW; i += 256) {
        const int r_ = i / GRW, gi = i - r_ * GRW;
        *(u16x8*)&Wl[(r_ * GRW + (gi ^ (r_ & 7))) * 8] =
            *(const u16x8*)(WT + (size_t)(m0 + r_) * KP + gi * 8);
    }
    float bv[MT][4];
    #pragma unroll
    for (int mt = 0; mt < MT; ++mt)
        #pragma unroll
        for (int j = 0; j < 4; ++j)
            bv[mt][j] = bias[m0 + w * WR + mt * 16 + hi * 4 + j];
    __syncthreads();

    for (int t = phase; t < SEQT; t += P) {
        // ring-overwrite guard (downstream consumption progress)
        if (w == 0) {
            int gd = 0; bool ok;
            do {
                bool pr = true;
                for (int i = lane; i < nGd; i += 64)
                    pr = pr && ((int)ald(&Fguard[i * 16]) >= t - 15);
                ok = __all(pr);
                if (!ok) __builtin_amdgcn_s_sleep(16);
            } while (!ok && ++gd < LIM);
        }

        const unsigned* hslab = hring + (size_t)(t & (RING - 1)) * 128 * KP;
        const unsigned exp = (unsigned)(t + 1);

        f32x4 acc[MT][8];
        #pragma unroll
        for (int mt = 0; mt < MT; ++mt)
            #pragma unroll
            for (int nn = 0; nn < 8; ++nn) acc[mt][nn] = f32x4{0.f, 0.f, 0.f, 0.f};

        for (int kc = 0; kc < NC; ++kc) {
            u32x4 cw[4];
            const unsigned* cp = hslab + (size_t)crow * KP + kc * 32 + ccol;
            #pragma unroll
            for (int q = 0; q < 4; ++q) ld4u(&cw[q], cp + q * 4);
            wait0();
            int gd = 0;
            for (;;) {
                bool ok = true;
                #pragma unroll
                for (int q = 0; q < 4; ++q)
                    #pragma unroll
                    for (int e = 0; e < 4; ++e)
                        ok = ok && ((cw[q][e] >> 16) == exp);
                if (ok || ++gd >= LIM) break;
                __builtin_amdgcn_s_sleep(2);
                #pragma unroll
                for (int q = 0; q < 4; ++q) ld4u(&cw[q], cp + q * 4);
                wait0();
            }
            #pragma unroll
            for (int gq2 = 0; gq2 < 2; ++gq2) {
                u16x8 v;
                #pragma unroll
                for (int e = 0; e < 4; ++e) v[e]     = (ushortT)cw[gq2 * 2][e];
                #pragma unroll
                for (int e = 0; e < 4; ++e) v[4 + e] = (ushortT)cw[gq2 * 2 + 1][e];
                const int g4 = cg0 + gq2;
                *(u16x8*)&Xl[crow * 32 + (g4 ^ ((crow >> 1) & 3)) * 8] = v;
            }
            __syncthreads();
            #pragma unroll
            for (int mt = 0; mt < MT; ++mt) {
                const int arow = w * WR + mt * 16 + lo;
                const int gsa = (kc * 4 + hi) ^ (arow & 7);
                const bf16x8 a = *(const bf16x8*)&Wl[(arow * GRW + gsa) * 8];
                #pragma unroll
                for (int nn = 0; nn < 8; ++nn) {
                    const int brow = nn * 16 + lo;
                    const bf16x8 b = *(const bf16x8*)&Xl[brow * 32 + (hi ^ ((brow >> 1) & 3)) * 8];
                    acc[mt][nn] = __builtin_amdgcn_mfma_f32_16x16x32_bf16(a, b, acc[mt][nn], 0, 0, 0);
                }
            }
            __syncthreads();
        }

        // tagged xg stores (fire-and-forget)
        unsigned* xb = xgring + (size_t)(t & (RING - 1)) * 8 * NG * 16;
        const unsigned tg = ((unsigned)(t + 1)) << 16;
        #pragma unroll
        for (int mt = 0; mt < MT; ++mt)
            #pragma unroll
            for (int nn = 0; nn < 8; ++nn)
                #pragma unroll
                for (int j = 0; j < 4; ++j) {
                    const int m = m0 + w * WR + mt * 16 + hi * 4 + j;
                    st4c(xb + ((size_t)nn * NG + m) * 16 + lo,
                         tg | (unsigned)f2bf(acc[mt][nn][j] + bv[mt][j]));
                }
        if (tid == 0) ast(Fpub, (unsigned)(t + 1));
    }
}

// ---------------------------------------------------------------------------
// Megakernel. Grid 224 x 256 thr, 1 WG/CU.
//  [0,32) L0  [32,96) L1  [96,128) L2  [128,192) G1 (8mt x 8ph)  [192,224) G2 (8mt x 4ph)
// ---------------------------------------------------------------------------
struct MegaArgs {
    const float *U0, *U1, *U2;
    const ushortT *W1T, *W2T;
    const float *b1, *b2;
    const ushortT* xg0;
    unsigned *xg1, *xg2;
    unsigned *h0r, *h1r, *h2r;
    unsigned *FL1, *FL2, *FG1, *FG2;
};

__global__ __launch_bounds__(256, 1) void mega(MegaArgs A)
{
    extern __shared__ char smem[];
    const int bid = blockIdx.x;
    if (bid < 32) {
        rec_role<NU0, false, 15>(bid, A.U0, A.xg0, 511, A.h0r,
                                 A.FG1, 64, nullptr, smem);
    } else if (bid < 96) {
        rec_role<NU1, true, 11>(bid - 32, A.U1, A.xg1, RING - 1, A.h1r,
                                A.FG2, 32, A.FL1 + (bid - 32) * 16, smem);
    } else if (bid < 128) {
        rec_role<NU2, true, 15>(bid - 96, A.U2, A.xg2, RING - 1, A.h2r,
                                nullptr, 0, A.FL2 + (bid - 96) * 16, smem);
    } else if (bid < 192) {
        const int wid = bid - 128;
        const int mt = wid & 7, ph = wid >> 3;
        worker_role<256, 2048, 256, 8>(mt, ph, A.W1T, A.b1, A.h0r, A.xg1,
                                       A.FL1, 64, A.FG1 + wid * 16, smem);
    } else {
        const int wid = bid - 192;
        const int mt = wid & 7, ph = wid >> 3;
        worker_role<128, 1024, 512, 4>(mt, ph, A.W2T, A.b2, A.h1r, A.xg2,
                                       A.FL2, 32, A.FG2 + wid * 16, smem);
    }
}

// ---------------------------------------------------------------------------
// Head: h2r tagged u32 [RING][128][256]; final t=511 -> slab 15, low 16 bits.
// ---------------------------------------------------------------------------
__global__ __launch_bounds__(64) void head_kernel(
    const unsigned* __restrict__ h2r,
    const float* __restrict__ Wd,
    const float* __restrict__ bd,
    const float* __restrict__ Wc,
    const float* __restrict__ bc,
    float* __restrict__ out)
{
    const int b = blockIdx.x;
    const int j = threadIdx.x;
    const unsigned* hrow = h2r + ((size_t)15 * 128 + b) * NU2;
    float a = bd[j];
    #pragma unroll 4
    for (int k = 0; k < NU2; ++k)
        a += bf2f((ushortT)hrow[k]) * Wd[(size_t)k * NDENSE + j];
    a = fmaxf(a, 0.f) * Wc[j];
    #pragma unroll
    for (int off = 32; off > 0; off >>= 1)
        a += __shfl_down(a, off);
    if (j == 0)
        out[b] = 1.f / (1.f + expf(-(a + bc[0])));
}

// ---------------------------------------------------------------------------
extern "C" void kernel_launch(void* const* d_in, const int* in_sizes, int n_in,
                              void* d_out, int out_size, void* d_ws, size_t ws_size,
                              hipStream_t stream)
{
    const int*   tokens = (const int*)  d_in[0];
    const float* emb    = (const float*)d_in[1];
    const float* W0     = (const float*)d_in[2];
    const float* Ur0    = (const float*)d_in[3];
    const float* b0v    = (const float*)d_in[4];
    const float* W1     = (const float*)d_in[5];
    const float* Ur1    = (const float*)d_in[6];
    const float* b1v    = (const float*)d_in[7];
    const float* W2     = (const float*)d_in[8];
    const float* Ur2    = (const float*)d_in[9];
    const float* b2v    = (const float*)d_in[10];
    const float* Wd     = (const float*)d_in[11];
    const float* bd     = (const float*)d_in[12];
    const float* Wc     = (const float*)d_in[13];
    const float* bc     = (const float*)d_in[14];
    float* out = (float*)d_out;

    char* p = (char*)d_ws;
    auto alloc = [&](size_t bytes) -> char* {
        char* q = p; p += (bytes + 255) & ~(size_t)255; return q;
    };
    ushortT*  xg0  = (ushortT*)alloc((size_t)SEQT * 8 * 1024 * 16 * 2);   // 128 MB
    unsigned* xg1  = (unsigned*)alloc((size_t)RING * 8 * 2048 * 16 * 4);  // 16 MB
    unsigned* xg2  = (unsigned*)alloc((size_t)RING * 8 * 1024 * 16 * 4);  // 8 MB
    unsigned* h0r  = (unsigned*)alloc((size_t)RING * 128 * NU0 * 4);      // 2 MB
    unsigned* h1r  = (unsigned*)alloc((size_t)RING * 128 * NU1 * 4);      // 4 MB
    unsigned* h2r  = (unsigned*)alloc((size_t)RING * 128 * NU2 * 4);      // 2 MB
    ushortT*  W0T  = (ushortT*)alloc((size_t)1024 * KP0 * 2);
    ushortT*  W1T  = (ushortT*)alloc((size_t)2048 * NU0 * 2);
    ushortT*  W2T  = (ushortT*)alloc((size_t)1024 * NU1 * 2);
    ushortT*  embbf= (ushortT*)alloc((size_t)VOCABN * KP0 * 2);
    unsigned* flg  = (unsigned*)alloc(16384);

    unsigned* FL1 = flg;             // 64
    unsigned* FL2 = flg + 64 * 16;   // 32
    unsigned* FG1 = flg + 96 * 16;   // 64
    unsigned* FG2 = flg + 160 * 16;  // 32

    // zero tags + flags every launch (replay-safe, deterministic)
    hipMemsetAsync(xg1, 0, (size_t)RING * 8 * 2048 * 16 * 4, stream);
    hipMemsetAsync(xg2, 0, (size_t)RING * 8 * 1024 * 16 * 4, stream);
    hipMemsetAsync(h0r, 0, (size_t)RING * 128 * NU0 * 4, stream);
    hipMemsetAsync(h1r, 0, (size_t)RING * 128 * NU1 * 4, stream);
    hipMemsetAsync(h2r, 0, (size_t)RING * 128 * NU2 * 4, stream);
    hipMemsetAsync(flg, 0, 16384, stream);

    convert_WT<<<512, 256, 0, stream>>>(W0, W0T, EMB_D, 1024, KP0, 1024 * KP0);
    convert_WT<<<512, 256, 0, stream>>>(W1, W1T, NU0, 2048, NU0, 2048 * NU0);
    convert_WT<<<512, 256, 0, stream>>>(W2, W2T, NU1, 1024, NU1, 1024 * NU1);
    convert_emb<<<1024, 256, 0, stream>>>(emb, embbf);

    gemm_xg0<<<dim3(SEQT, 8), 256, 0, stream>>>(embbf, tokens, W0T, b0v, xg0);

    MegaArgs A;
    A.U0 = Ur0; A.U1 = Ur1; A.U2 = Ur2;
    A.W1T = W1T; A.W2T = W2T;
    A.b1 = b1v; A.b2 = b2v;
    A.xg0 = xg0; A.xg1 = xg1; A.xg2 = xg2;
    A.h0r = h0r; A.h1r = h1r; A.h2r = h2r;
    A.FL1 = FL1; A.FL2 = FL2; A.FG1 = FG1; A.FG2 = FG2;

    void* args[] = {&A};
    // smem: worker = MC*KP*2 (131072) + 128*32*2 (8192) = 139264 (max role)
    hipLaunchCooperativeKernel((void*)mega, dim3(224), dim3(256), args, 139264, stream);

    head_kernel<<<BATCH, 64, 0, stream>>>(h2r, Wd, bd, Wc, bc, out);
}